// Round 12
// baseline (266.641 us; speedup 1.0000x reference)
//
#include <hip/hip_runtime.h>
#include <cstdint>

#define Ltok 4096
#define Dm   2048

typedef __attribute__((ext_vector_type(8))) short short8;
typedef __attribute__((ext_vector_type(4))) float f32x4;
typedef __attribute__((ext_vector_type(4))) int   i32x4;

static __device__ __forceinline__ ushort f2bf(float x) {
  union { float f; uint32_t u; } v; v.f = x;
  uint32_t r = v.u + 0x7FFFu + ((v.u >> 16) & 1u);
  return (ushort)(r >> 16);
}
static __device__ __forceinline__ signed char q8(float x) {
  x = fminf(fmaxf(x, -127.0f), 127.0f);
  return (signed char)(int)rintf(x);
}

typedef __attribute__((address_space(1))) void gv_t;
typedef __attribute__((address_space(3))) void lv_t;
static __device__ __forceinline__ void lds_load16(const void* g, void* l) {
  __builtin_amdgcn_global_load_lds((gv_t*)g, (lv_t*)l, 16, 0, 0);
}

// ---------------------------------------------------------------------------
// prep: row norm + bf16 cast + i8 cast (scale 127/5) + packed params
__global__ __launch_bounds__(256) void prep_tokens(const float* __restrict__ T,
                                                   const float* __restrict__ ecc,
                                                   const int* __restrict__ pos,
                                                   const int* __restrict__ dep,
                                                   ushort* __restrict__ Tbf,
                                                   signed char* __restrict__ Tq,
                                                   float4* __restrict__ tokf4) {
  __shared__ float red[4];
  const int tid = threadIdx.x, lane = tid & 63, w = tid >> 6;
  const int row = blockIdx.x;
  const float* rp = T + (size_t)row * Dm;
  ushort* op = Tbf + (size_t)row * Dm;
  signed char* oq = Tq + (size_t)row * Dm;
  float ss = 0.f;
  for (int j = tid * 4; j < Dm; j += 1024) {
    float4 v = *(const float4*)&rp[j];
    ss += v.x * v.x + v.y * v.y + v.z * v.z + v.w * v.w;
    ushort4 o; o.x = f2bf(v.x); o.y = f2bf(v.y); o.z = f2bf(v.z); o.w = f2bf(v.w);
    *(ushort4*)&op[j] = o;
    char4 q; q.x = q8(v.x * 25.4f); q.y = q8(v.y * 25.4f);
    q.z = q8(v.z * 25.4f); q.w = q8(v.w * 25.4f);
    *(char4*)&oq[j] = q;
  }
#pragma unroll
  for (int off = 32; off > 0; off >>= 1) ss += __shfl_xor(ss, off);
  if (lane == 0) red[w] = ss;
  __syncthreads();
  if (tid == 0) {
    float n = sqrtf(red[0] + red[1] + red[2] + red[3]);
    int d = dep[row];
    float4 t;
    t.x = n / (n + 1e-8f);
    t.y = ecc[row];
    t.z = (d <= 0) ? 1.0f : (d == 1 ? 3.0f : 9.0f);
    t.w = (float)pos[row];
    tokf4[row] = t;
  }
}

// weights f32 -> i8 at scale 127/0.125 = 1016
__global__ __launch_bounds__(256) void cast_f32_i8(const float* __restrict__ in,
                                                   signed char* __restrict__ out, int n) {
  int i = (blockIdx.x * 256 + threadIdx.x) * 4;
  if (i + 3 < n) {
    float4 v = *(const float4*)&in[i];
    char4 q; q.x = q8(v.x * 1016.0f); q.y = q8(v.y * 1016.0f);
    q.z = q8(v.z * 1016.0f); q.w = q8(v.w * 1016.0f);
    *(char4*)&out[i] = q;
  }
}

__global__ void small_prep(const float* __restrict__ G, const float* __restrict__ R,
                           float* __restrict__ sGR) {
  int tid = threadIdx.x;
  if (tid < 64) {
    float g = 1.0f / (1.0f + expf(-G[tid]));
    float r = 1.0f / (1.0f + expf(-R[tid]));
    sGR[tid] = g * r;
  }
}

// ---------------------------------------------------------------------------
#define FENCE asm volatile("" ::: "memory")
#define PH_MID { FENCE; __builtin_amdgcn_s_barrier(); __builtin_amdgcn_s_setprio(1); }
#define PH_END { __builtin_amdgcn_s_setprio(0); FENCE; __builtin_amdgcn_s_barrier(); FENCE; }
#define PH_ENDV1 { __builtin_amdgcn_s_setprio(0); FENCE; \
                  asm volatile("s_waitcnt vmcnt(1)" ::: "memory"); \
                  __builtin_amdgcn_s_barrier(); FENCE; }

// inverse swizzle within an 8KB unit, byte-addressed ([128 rows][64 bytes])
#define INV_SWZ8B(P, ROW, COLB) { \
  int s_ = (P) >> 10, ww_ = (P) & 1023; \
  ww_ ^= ((ww_ >> 9) & 1) << 5; \
  ROW = (s_ << 4) + (ww_ >> 6); \
  COLB = ww_ & 63; }

// ===========================================================================
// gemm_sym: scores via SYMMETRY.  C = scale(T @ T^T), 128x128 tiles, only
// lower-triangle tile pairs (ti >= tj), mirror-write the transpose.
// Round-3-proven 2-phase kernel body (4 waves, BK=32, 16KB LDS, ~5 blk/CU).
// 528 = 32*33/2 blocks = 8*66 (XCD swizzle ok).
__global__ __launch_bounds__(256) void gemm_sym(
    const ushort* __restrict__ A,
    float* __restrict__ Cf,
    const float4* __restrict__ tokf4, const float* __restrict__ sGR)
{
  __shared__ ushort sA[128 * 32];
  __shared__ ushort sB[128 * 32];
  const int tid = threadIdx.x;
  const int lane = tid & 63;
  const int w = tid >> 6;
  const int wr = w >> 1, wc = w & 1;
  const int fr = lane & 15, fq = lane >> 4;

  // XCD swizzle + triangle decode
  int b = blockIdx.x;
  int s = (b & 7) * 66 + (b >> 3);
  int ti = (int)((sqrtf(8.0f * (float)s + 1.0f) - 1.0f) * 0.5f);
  while ((ti + 1) * (ti + 2) / 2 <= s) ++ti;
  while (ti * (ti + 1) / 2 > s) --ti;
  const int tj = s - ti * (ti + 1) / 2;
  const int bm = ti * 128, bn = tj * 128;

  const int q = w * 2;
  const int e0 = q * 512 + lane * 8;
  const int rA = e0 >> 5, cA = e0 & 31;
  const ushort* gA0 = A + (size_t)(bm + rA) * Dm + cA;
  const ushort* gA1 = A + (size_t)(bm + rA + 16) * Dm + cA;
  const ushort* gB0 = A + (size_t)(bn + rA) * Dm + cA;
  const ushort* gB1 = A + (size_t)(bn + rA + 16) * Dm + cA;
  ushort* lA0 = &sA[q * 512]; ushort* lA1 = &sA[q * 512 + 512];
  ushort* lB0 = &sB[q * 512]; ushort* lB1 = &sB[q * 512 + 512];
  const ushort* fA = &sA[(wr * 64 + fr) * 32 + fq * 8];
  const ushort* fB = &sB[(wc * 64 + fr) * 32 + fq * 8];

  f32x4 acc[4][4] = {};

  for (int kt = 0; kt < Dm; kt += 32) {
    __syncthreads();
    lds_load16(gA0 + kt, lA0);
    lds_load16(gA1 + kt, lA1);
    lds_load16(gB0 + kt, lB0);
    lds_load16(gB1 + kt, lB1);
    __syncthreads();
    short8 af[4], bfr[4];
#pragma unroll
    for (int m = 0; m < 4; ++m) af[m] = *(const short8*)(fA + m * 16 * 32);
#pragma unroll
    for (int n = 0; n < 4; ++n) bfr[n] = *(const short8*)(fB + n * 16 * 32);
#pragma unroll
    for (int m = 0; m < 4; ++m)
#pragma unroll
      for (int n = 0; n < 4; ++n)
        acc[m][n] = __builtin_amdgcn_mfma_f32_16x16x32_bf16(af[m], bfr[n], acc[m][n], 0, 0, 0);
  }

  // epilogue: scale, zero diag, dual write (direct gi>=gj, mirror gi>gj)
  const int gj0 = bn + wc * 64 + fr;
  const int gi0 = bm + wr * 64 + fq * 4;
  float4 cj[4];
#pragma unroll
  for (int n = 0; n < 4; ++n) cj[n] = tokf4[gj0 + n * 16];
#pragma unroll
  for (int m = 0; m < 4; ++m) {
#pragma unroll
    for (int r = 0; r < 4; ++r) {
      const int gi = gi0 + m * 16 + r;
      float4 ci = tokf4[gi];
#pragma unroll
      for (int n = 0; n < 4; ++n) {
        const int gj = gj0 + n * 16;
        float x = acc[m][n][r];
        float rr = fabsf(ci.z - cj[n].z) + 1.0f;
        int pi = (int)ci.w, pj = (int)cj[n].w;
        float c = sGR[pi * 8 + pj] * (1.0f - ci.y * cj[n].y) *
                  (ci.x * cj[n].x) * __builtin_amdgcn_rcpf(rr * rr);
        x *= c;
        if (gi == gj) x = 0.0f;
        if (gi >= gj) Cf[(size_t)gi * Ltok + gj] = x;
        if (gi > gj)  Cf[(size_t)gj * Ltok + gi] = x;
      }
    }
  }
}

// ===========================================================================
// gemm4i: i8 GEMM, 128x256 tile, BK=64 bytes, 8 waves, 4-phase, 48KB LDS.
// MODE 0: AV  -> i8  (q = rint(acc * sRow[gi]))
// MODE 1: V   -> i8  (q = rint((acc*CV + bias[gi]) * 127/8))
// MODE 2: out -> f32 (acc*CO + bias[gj])
#define STI_A(BUF,KT) \
  lds_load16(sAs + (size_t)(KT)*64, lbase + (BUF)*24576 + tid*16);
#define STI_BH(BUF,H,KT) \
  lds_load16(sBs + (size_t)(H)*128*KDIM + (size_t)(KT)*64, lbase + (BUF)*24576 + 8192 + (H)*8192 + tid*16);
#define RDI_A(BUF) { _Pragma("unroll") for (int m_ = 0; m_ < 4; ++m_) \
    ai[m_] = *(const i32x4*)(lbase + (BUF)*24576 + baseA + m_*1024); }
#define RDI_B(BUF,NIB) { _Pragma("unroll") for (int n_ = 0; n_ < 2; ++n_) \
    bi[n_] = *(const i32x4*)(lbase + (BUF)*24576 + baseB + ((NIB)+n_)*1024); }
#define MFI_P(NIB) { _Pragma("unroll") for (int m_ = 0; m_ < 4; ++m_) \
  _Pragma("unroll") for (int n_ = 0; n_ < 2; ++n_) \
    acc[m_][(NIB)+n_] = __builtin_amdgcn_mfma_i32_16x16x64_i8(ai[m_], bi[n_], acc[m_][(NIB)+n_], 0, 0, 0); }

template <int MODE, int NDIM, int KDIM>
__global__ __launch_bounds__(512, 2) void gemm4i(
    const signed char* __restrict__ A, const signed char* __restrict__ B,
    signed char* __restrict__ C8, float* __restrict__ Cf,
    const float* __restrict__ sRow, const float* __restrict__ bias)
{
  constexpr int NT = KDIM / 64;
  constexpr int NI = NT / 2;
  __shared__ __align__(16) char lds_raw[49152];
  char* lbase = lds_raw;

  const int tid = threadIdx.x;
  const int lane = tid & 63;
  const int w0 = tid >> 6;
  const int wr = w0 >> 2, wc = w0 & 3;
  const int fr = lane & 15, fq = lane >> 4;

  int gx = gridDim.x;
  int bid = blockIdx.y * gx + blockIdx.x;
  int cpx = (gx * gridDim.y) >> 3;
  int sbid = (bid & 7) * cpx + (bid >> 3);
  const int bn = (sbid % gx) * 256;
  const int bm = (sbid / gx) * 128;

  int rS, cSB;
  INV_SWZ8B(tid * 16, rS, cSB)
  const signed char* sAs = A + (size_t)(bm + rS) * KDIM + cSB;
  const signed char* sBs = B + (size_t)(bn + rS) * KDIM + cSB;

  const int lanep = (fr * 64 + fq * 16) ^ ((fr & 8) << 2);
  const int baseA = wr * 4096 + lanep;
  const int baseB = 8192 + wc * 4096 + lanep;

  i32x4 ai[4], bi[2];
  i32x4 acc[4][4] = {};

  STI_A(0, 0) STI_BH(0, 0, 0) STI_BH(0, 1, 0)
  STI_A(1, 1)
  FENCE;
  asm volatile("s_waitcnt vmcnt(1)" ::: "memory");
  __builtin_amdgcn_s_barrier();
  FENCE;

#pragma unroll 1
  for (int it = 0; it < NI; ++it) {
    const int t1 = 2 * it + 1;
    const int t2 = (2 * it + 2 < NT) ? 2 * it + 2 : NT - 1;
    const int t3 = (2 * it + 3 < NT) ? 2 * it + 3 : NT - 1;
    RDI_A(0) RDI_B(0, 0) STI_BH(1, 0, t1) STI_BH(1, 1, t1)
    PH_MID MFI_P(0) PH_END
    RDI_B(0, 2) STI_A(0, t2)
    PH_MID MFI_P(2) PH_ENDV1
    RDI_A(1) RDI_B(1, 0) STI_BH(0, 0, t2) STI_BH(0, 1, t2)
    PH_MID MFI_P(0) PH_END
    RDI_B(1, 2) STI_A(1, t3)
    PH_MID MFI_P(2) PH_ENDV1
  }

  // ---- epilogue ----
  const int gj0 = bn + wc * 64 + fr;
  const int gi0 = bm + wr * 64 + fq * 4;

  if constexpr (MODE == 0) {
#pragma unroll
    for (int m = 0; m < 4; ++m)
#pragma unroll
      for (int r = 0; r < 4; ++r) {
        const int gi = gi0 + m * 16 + r;
        float sa = sRow[gi];
#pragma unroll
        for (int n = 0; n < 4; ++n)
          C8[(size_t)gi * NDIM + gj0 + n * 16] = q8((float)acc[m][n][r] * sa);
      }
  } else if constexpr (MODE == 1) {
    const float CV = 0.625f / 16129.0f;        // (5/127)*(0.125/127)
#pragma unroll
    for (int m = 0; m < 4; ++m)
#pragma unroll
      for (int r = 0; r < 4; ++r) {
        const int gi = gi0 + m * 16 + r;
        float rb = bias[gi];
#pragma unroll
        for (int n = 0; n < 4; ++n)
          C8[(size_t)gi * NDIM + gj0 + n * 16] =
              q8(((float)acc[m][n][r] * CV + rb) * 15.875f);
      }
  } else {
    const float CO = 1.0f / 16129.0f;          // (8/127)*(0.125/127)
    float cb[4];
#pragma unroll
    for (int n = 0; n < 4; ++n) cb[n] = bias[gj0 + n * 16];
#pragma unroll
    for (int m = 0; m < 4; ++m)
#pragma unroll
      for (int r = 0; r < 4; ++r) {
        const int gi = gi0 + m * 16 + r;
#pragma unroll
        for (int n = 0; n < 4; ++n)
          Cf[(size_t)gi * NDIM + gj0 + n * 16] = (float)acc[m][n][r] * CO + cb[n];
      }
  }
}

// ---------------------------------------------------------------------------
// softmax: f32 A -> d_out, i8 A (q = round(exp*127)) + row scale -> ws
__global__ __launch_bounds__(256) void softmax_rows(const float* __restrict__ S,
                                                    float* __restrict__ Af,
                                                    signed char* __restrict__ Aq,
                                                    float* __restrict__ sRowA) {
  __shared__ float buf[Ltok];
  __shared__ float red[4];
  const int tid = threadIdx.x, lane = tid & 63, w = tid >> 6;
  const float LOG2E = 1.44269504088896f;
  const float* sr = S + (size_t)blockIdx.x * Ltok;
  float lmax = -3.4e38f;
  for (int j = tid * 4; j < Ltok; j += 1024) {
    float4 v = *(const float4*)&sr[j];
    *(float4*)&buf[j] = v;
    lmax = fmaxf(fmaxf(lmax, fmaxf(v.x, v.y)), fmaxf(v.z, v.w));
  }
#pragma unroll
  for (int off = 32; off > 0; off >>= 1) lmax = fmaxf(lmax, __shfl_xor(lmax, off));
  if (lane == 0) red[w] = lmax;
  __syncthreads();
  const float m = fmaxf(fmaxf(red[0], red[1]), fmaxf(red[2], red[3])) * LOG2E;
  __syncthreads();
  float lsum = 0.f;
  for (int j = tid * 4; j < Ltok; j += 1024) {
    lsum += exp2f(buf[j] * LOG2E - m) + exp2f(buf[j + 1] * LOG2E - m) +
            exp2f(buf[j + 2] * LOG2E - m) + exp2f(buf[j + 3] * LOG2E - m);
  }
#pragma unroll
  for (int off = 32; off > 0; off >>= 1) lsum += __shfl_xor(lsum, off);
  if (lane == 0) red[w] = lsum;
  __syncthreads();
  const float inv = 1.0f / (red[0] + red[1] + red[2] + red[3]);
  if (tid == 0) sRowA[blockIdx.x] = inv * (1.0f / 127.0f);
  float* arf = Af + (size_t)blockIdx.x * Ltok;
  signed char* arq = Aq + (size_t)blockIdx.x * Ltok;
  for (int j = tid * 4; j < Ltok; j += 1024) {
    float e0 = exp2f(buf[j] * LOG2E - m);
    float e1 = exp2f(buf[j + 1] * LOG2E - m);
    float e2 = exp2f(buf[j + 2] * LOG2E - m);
    float e3 = exp2f(buf[j + 3] * LOG2E - m);
    float4 aa; aa.x = e0 * inv; aa.y = e1 * inv; aa.z = e2 * inv; aa.w = e3 * inv;
    *(float4*)&arf[j] = aa;
    char4 q;
    q.x = (signed char)(int)rintf(e0 * 127.0f);
    q.y = (signed char)(int)rintf(e1 * 127.0f);
    q.z = (signed char)(int)rintf(e2 * 127.0f);
    q.w = (signed char)(int)rintf(e3 * 127.0f);
    *(char4*)&arq[j] = q;
  }
}

// ---------------------------------------------------------------------------
extern "C" void kernel_launch(void* const* d_in, const int* in_sizes, int n_in,
                              void* d_out, int out_size, void* d_ws, size_t ws_size,
                              hipStream_t stream) {
  const float* tok = (const float*)d_in[0];
  const float* ecc = (const float*)d_in[1];
  const float* Gm  = (const float*)d_in[2];
  const float* Rm  = (const float*)d_in[3];
  const float* Wv  = (const float*)d_in[4];
  const float* bv  = (const float*)d_in[5];
  const float* Wo  = (const float*)d_in[6];
  const float* bo  = (const float*)d_in[7];
  const int*   pos = (const int*)d_in[8];
  const int*   dep = (const int*)d_in[9];

  float* out_f = (float*)d_out;                    // [L][D] f32
  float* A_f   = out_f + (size_t)Ltok * Dm;        // [L][L] f32
  float* S_f   = A_f + (size_t)Ltok * Ltok;        // [L][L] f32

  char* ws = (char*)d_ws;
  size_t off = 0;
  auto alloc = [&](size_t bytes) {
    void* p = ws + off; off = (off + bytes + 255) & ~(size_t)255; return p;
  };
  ushort*      Tbf = (ushort*)alloc((size_t)Ltok * Dm * 2);      // 16 MB
  signed char* Tq  = (signed char*)alloc((size_t)Ltok * Dm);     //  8 MB
  signed char* Wvq = (signed char*)alloc((size_t)Dm * Dm);       //  4 MB
  signed char* Woq = (signed char*)alloc((size_t)Dm * Dm);       //  4 MB
  signed char* Vtq = (signed char*)alloc((size_t)Dm * Ltok);     //  8 MB
  signed char* Aq  = (signed char*)alloc((size_t)Ltok * Ltok);   // 16 MB
  signed char* AVq = (signed char*)alloc((size_t)Ltok * Dm);     //  8 MB
  float4* tokf4 = (float4*)alloc(Ltok * 16);
  float*  sGR  = (float*)alloc(64 * 4);
  float*  sRowA = (float*)alloc(Ltok * 4);

  prep_tokens<<<Ltok, 256, 0, stream>>>(tok, ecc, pos, dep, Tbf, Tq, tokf4);
  cast_f32_i8<<<(Dm * Dm) / 1024, 256, 0, stream>>>(Wv, Wvq, Dm * Dm);
  cast_f32_i8<<<(Dm * Dm) / 1024, 256, 0, stream>>>(Wo, Woq, Dm * Dm);
  small_prep<<<1, 64, 0, stream>>>(Gm, Rm, sGR);

  // scores via symmetry: 528 lower-triangle 128x128 tiles, mirror-write
  gemm_sym<<<528, 256, 0, stream>>>(Tbf, S_f, tokf4, sGR);
  // A = softmax(scores): f32 -> d_out, i8 + row scale -> ws
  softmax_rows<<<Ltok, 256, 0, stream>>>(S_f, A_f, Aq, sRowA);

  // V^T[d][l] i8 = quant(Wvq . Tq * CV + bv)   (grid 16x16 = 256 blocks)
  gemm4i<1, Ltok, Dm><<<dim3(Ltok / 256, Dm / 128), 512, 0, stream>>>(
      Wvq, Tq, Vtq, nullptr, nullptr, bv);

  // AV i8 = quant(Aq @ Vtq * sRow)   (grid 8x32 = 256 blocks)
  gemm4i<0, Dm, Ltok><<<dim3(Dm / 256, Ltok / 128), 512, 0, stream>>>(
      Aq, Vtq, AVq, nullptr, sRowA, nullptr);

  // out f32 = AVq @ Woq * CO + bo   (grid 8x32 = 256 blocks)
  gemm4i<2, Dm, Dm><<<dim3(Dm / 256, Ltok / 128), 512, 0, stream>>>(
      AVq, Woq, nullptr, out_f, nullptr, bo);
}

// Round 13
// 212.366 us; speedup vs baseline: 1.2556x; 1.2556x over previous
//
#include <hip/hip_runtime.h>
#include <cstdint>

#define Ltok 4096
#define Dm   2048

typedef __attribute__((ext_vector_type(8))) short short8;
typedef __attribute__((ext_vector_type(4))) float f32x4;
typedef __attribute__((ext_vector_type(4))) int   i32x4;

static __device__ __forceinline__ ushort f2bf(float x) {
  union { float f; uint32_t u; } v; v.f = x;
  uint32_t r = v.u + 0x7FFFu + ((v.u >> 16) & 1u);
  return (ushort)(r >> 16);
}
static __device__ __forceinline__ signed char q8(float x) {
  x = fminf(fmaxf(x, -127.0f), 127.0f);
  return (signed char)(int)rintf(x);
}

typedef __attribute__((address_space(1))) void gv_t;
typedef __attribute__((address_space(3))) void lv_t;
static __device__ __forceinline__ void lds_load16(const void* g, void* l) {
  __builtin_amdgcn_global_load_lds((gv_t*)g, (lv_t*)l, 16, 0, 0);
}

// ---------------------------------------------------------------------------
// prep: row norm + bf16 cast + i8 cast (scale 127/5) + packed params
__global__ __launch_bounds__(256) void prep_tokens(const float* __restrict__ T,
                                                   const float* __restrict__ ecc,
                                                   const int* __restrict__ pos,
                                                   const int* __restrict__ dep,
                                                   ushort* __restrict__ Tbf,
                                                   signed char* __restrict__ Tq,
                                                   float4* __restrict__ tokf4) {
  __shared__ float red[4];
  const int tid = threadIdx.x, lane = tid & 63, w = tid >> 6;
  const int row = blockIdx.x;
  const float* rp = T + (size_t)row * Dm;
  ushort* op = Tbf + (size_t)row * Dm;
  signed char* oq = Tq + (size_t)row * Dm;
  float ss = 0.f;
  for (int j = tid * 4; j < Dm; j += 1024) {
    float4 v = *(const float4*)&rp[j];
    ss += v.x * v.x + v.y * v.y + v.z * v.z + v.w * v.w;
    ushort4 o; o.x = f2bf(v.x); o.y = f2bf(v.y); o.z = f2bf(v.z); o.w = f2bf(v.w);
    *(ushort4*)&op[j] = o;
    char4 q; q.x = q8(v.x * 25.4f); q.y = q8(v.y * 25.4f);
    q.z = q8(v.z * 25.4f); q.w = q8(v.w * 25.4f);
    *(char4*)&oq[j] = q;
  }
#pragma unroll
  for (int off = 32; off > 0; off >>= 1) ss += __shfl_xor(ss, off);
  if (lane == 0) red[w] = ss;
  __syncthreads();
  if (tid == 0) {
    float n = sqrtf(red[0] + red[1] + red[2] + red[3]);
    int d = dep[row];
    float4 t;
    t.x = n / (n + 1e-8f);
    t.y = ecc[row];
    t.z = (d <= 0) ? 1.0f : (d == 1 ? 3.0f : 9.0f);
    t.w = (float)pos[row];
    tokf4[row] = t;
  }
}

// weights f32 -> i8 at scale 127/0.125 = 1016
__global__ __launch_bounds__(256) void cast_f32_i8(const float* __restrict__ in,
                                                   signed char* __restrict__ out, int n) {
  int i = (blockIdx.x * 256 + threadIdx.x) * 4;
  if (i + 3 < n) {
    float4 v = *(const float4*)&in[i];
    char4 q; q.x = q8(v.x * 1016.0f); q.y = q8(v.y * 1016.0f);
    q.z = q8(v.z * 1016.0f); q.w = q8(v.w * 1016.0f);
    *(char4*)&out[i] = q;
  }
}

__global__ void small_prep(const float* __restrict__ G, const float* __restrict__ R,
                           float* __restrict__ sGR) {
  int tid = threadIdx.x;
  if (tid < 64) {
    float g = 1.0f / (1.0f + expf(-G[tid]));
    float r = 1.0f / (1.0f + expf(-R[tid]));
    sGR[tid] = g * r;
  }
}

// ---------------------------------------------------------------------------
#define FENCE asm volatile("" ::: "memory")
#define PH_MID { FENCE; __builtin_amdgcn_s_barrier(); __builtin_amdgcn_s_setprio(1); }
#define PH_END { __builtin_amdgcn_s_setprio(0); FENCE; __builtin_amdgcn_s_barrier(); FENCE; }
#define PH_ENDV { __builtin_amdgcn_s_setprio(0); FENCE; \
                  asm volatile("s_waitcnt vmcnt(6)" ::: "memory"); \
                  __builtin_amdgcn_s_barrier(); FENCE; }
#define PH_ENDV1 { __builtin_amdgcn_s_setprio(0); FENCE; \
                  asm volatile("s_waitcnt vmcnt(1)" ::: "memory"); \
                  __builtin_amdgcn_s_barrier(); FENCE; }

// inverse st_16x32 swizzle within a 16KB unit (two 8KB halves x 2 col-blocks)
#define INV_SWZ(P, ROW, COL) { \
  int s_ = (P) >> 10, ww_ = (P) & 1023; \
  ww_ ^= ((ww_ >> 9) & 1) << 5; \
  ROW = ((s_ >> 1) << 4) + (ww_ >> 6); \
  COL = ((s_ & 1) << 5) + ((ww_ >> 1) & 31); }

// inverse swizzle within an 8KB unit, byte-addressed ([128 rows][64 bytes])
#define INV_SWZ8B(P, ROW, COLB) { \
  int s_ = (P) >> 10, ww_ = (P) & 1023; \
  ww_ ^= ((ww_ >> 9) & 1) << 5; \
  ROW = (s_ << 4) + (ww_ >> 6); \
  COLB = ww_ & 63; }

// ===========================================================================
// gemm8: 256x256 tile (BK=64, 8 waves 2Mx4N, per-wave 128x64), 8-phase.
// (round-6 proven form, scores epilogue)
#define ST_A(BUF,H,KT) { \
  lds_load16(sA0 + (size_t)(H)*128*KDIM + (size_t)(KT)*64, lbase + (BUF)*65536 + (H)*16384 + stW); \
  lds_load16(sA1 + (size_t)(H)*128*KDIM + (size_t)(KT)*64, lbase + (BUF)*65536 + (H)*16384 + 8192 + stW); }
#define ST_B(BUF,H,KT) { \
  lds_load16(sB0 + (size_t)(H)*128*KDIM + (size_t)(KT)*64, lbase + (BUF)*65536 + 32768 + (H)*16384 + stW); \
  lds_load16(sB1 + (size_t)(H)*128*KDIM + (size_t)(KT)*64, lbase + (BUF)*65536 + 32768 + (H)*16384 + 8192 + stW); }
#define DS_A(BUF,MIB) { _Pragma("unroll") for (int m_ = 0; m_ < 4; ++m_) \
  _Pragma("unroll") for (int kk_ = 0; kk_ < 2; ++kk_) \
    a[m_][kk_] = *(const short8*)(lbase + (BUF)*65536 + baseA + ((MIB)+m_)*2048 + kk_*1024); }
#define DS_B(BUF,NIB) { _Pragma("unroll") for (int n_ = 0; n_ < 2; ++n_) \
  _Pragma("unroll") for (int kk_ = 0; kk_ < 2; ++kk_) \
    bq[(NIB)+n_][kk_] = *(const short8*)(lbase + (BUF)*65536 + 32768 + baseB + ((NIB)+n_)*2048 + kk_*1024); }
#define MFMA_Q(MIB,NIB) { _Pragma("unroll") for (int m_ = 0; m_ < 4; ++m_) \
  _Pragma("unroll") for (int n_ = 0; n_ < 2; ++n_) { \
    acc[(MIB)+m_][(NIB)+n_] = __builtin_amdgcn_mfma_f32_16x16x32_bf16(a[m_][0], bq[(NIB)+n_][0], acc[(MIB)+m_][(NIB)+n_], 0, 0, 0); \
    acc[(MIB)+m_][(NIB)+n_] = __builtin_amdgcn_mfma_f32_16x16x32_bf16(a[m_][1], bq[(NIB)+n_][1], acc[(MIB)+m_][(NIB)+n_], 0, 0, 0); } }

template <int NDIM, int KDIM>
__global__ __launch_bounds__(512, 2) void gemm8(
    const ushort* __restrict__ A, const ushort* __restrict__ B,
    float* __restrict__ Cf,
    const float4* __restrict__ tokf4, const float* __restrict__ sGR)
{
  constexpr int NT = KDIM / 64;
  constexpr int NI = NT / 2;
  __shared__ __align__(16) char lds_raw[131072];
  char* lbase = lds_raw;

  const int tid = threadIdx.x;
  const int lane = tid & 63;
  const int w0 = tid >> 6;
  const int wr = w0 >> 2, wc = w0 & 3;
  const int fr = lane & 15, fq = lane >> 4;

  int gx = gridDim.x;
  int bid = blockIdx.y * gx + blockIdx.x;
  int cpx = (gx * gridDim.y) >> 3;
  int sbid = (bid & 7) * cpx + (bid >> 3);
  const int bn = (sbid % gx) * 256;
  const int bm = (sbid / gx) * 256;

  int rA0, cA0, rA1, cA1;
  INV_SWZ(tid * 16, rA0, cA0)
  INV_SWZ(tid * 16 + 8192, rA1, cA1)
  const ushort* sA0 = A + (size_t)(bm + rA0) * KDIM + cA0;
  const ushort* sA1 = A + (size_t)(bm + rA1) * KDIM + cA1;
  const ushort* sB0 = B + (size_t)(bn + rA0) * KDIM + cA0;
  const ushort* sB1 = B + (size_t)(bn + rA1) * KDIM + cA1;
  const int stW = w0 * 1024;

  const int lanep = (fr * 64 + fq * 16) ^ ((fr & 8) << 2);
  const int baseA = wr * 16384 + lanep;
  const int baseB = wc * 8192 + lanep;

  short8 a[4][2], bq[4][2];
  f32x4 acc[8][4] = {};

  ST_A(0, 0, 0) ST_A(0, 1, 0) ST_B(0, 0, 0) ST_B(0, 1, 0)
  ST_B(1, 0, 1) ST_A(1, 0, 1) ST_A(1, 1, 1)
  FENCE;
  asm volatile("s_waitcnt vmcnt(6)" ::: "memory");
  __builtin_amdgcn_s_barrier();
  FENCE;

#pragma unroll 1
  for (int it = 0; it < NI; ++it) {
    const int t1 = 2 * it + 1;
    const int t2 = (2 * it + 2 < NT) ? 2 * it + 2 : NT - 1;
    const int t3 = (2 * it + 3 < NT) ? 2 * it + 3 : NT - 1;
    DS_A(0, 0) DS_B(0, 0) ST_B(1, 1, t1)
    PH_MID MFMA_Q(0, 0) PH_END
    DS_B(0, 2)
    PH_MID MFMA_Q(0, 2) PH_END
    DS_A(0, 4) ST_B(0, 0, t2)
    PH_MID MFMA_Q(4, 2) PH_END
    ST_B(0, 1, t2) ST_A(0, 0, t2)
    PH_MID MFMA_Q(4, 0) PH_ENDV
    DS_A(1, 0) DS_B(1, 0) ST_A(0, 1, t2)
    PH_MID MFMA_Q(0, 0) PH_END
    DS_B(1, 2)
    PH_MID MFMA_Q(0, 2) PH_END
    DS_A(1, 4) ST_B(1, 0, t3)
    PH_MID MFMA_Q(4, 2) PH_END
    ST_A(1, 0, t3) ST_A(1, 1, t3)
    PH_MID MFMA_Q(4, 0) PH_ENDV
  }

  // ---- epilogue: scores ----
  const int gj0 = bn + wc * 64 + fr;
  const int gi0 = bm + wr * 128 + fq * 4;
  float4 cj[4];
#pragma unroll
  for (int n = 0; n < 4; ++n) cj[n] = tokf4[gj0 + n * 16];
#pragma unroll
  for (int m = 0; m < 8; ++m) {
#pragma unroll
    for (int r = 0; r < 4; ++r) {
      const int gi = gi0 + m * 16 + r;
      float4 ci = tokf4[gi];
#pragma unroll
      for (int n = 0; n < 4; ++n) {
        const int gj = gj0 + n * 16;
        float x = acc[m][n][r];
        float rr = fabsf(ci.z - cj[n].z) + 1.0f;
        int pi = (int)ci.w, pj = (int)cj[n].w;
        float c = sGR[pi * 8 + pj] * (1.0f - ci.y * cj[n].y) *
                  (ci.x * cj[n].x) * __builtin_amdgcn_rcpf(rr * rr);
        x *= c;
        if (gi == gj) x = 0.0f;
        Cf[(size_t)gi * NDIM + gj] = x;
      }
    }
  }
}

// ===========================================================================
// gemm4i: i8 GEMM, 128x256 tile, BK=64 bytes, 8 waves, 4-phase, 48KB LDS.
// MODE 0: AV  -> i8  (q = rint(acc * sRow[gi]))
// MODE 1: V   -> i8  (q = rint((acc*CV + bias[gi]) * 127/8))
// MODE 2: out -> f32 (acc*CO + bias[gj])
#define STI_A(BUF,KT) \
  lds_load16(sAs + (size_t)(KT)*64, lbase + (BUF)*24576 + tid*16);
#define STI_BH(BUF,H,KT) \
  lds_load16(sBs + (size_t)(H)*128*KDIM + (size_t)(KT)*64, lbase + (BUF)*24576 + 8192 + (H)*8192 + tid*16);
#define RDI_A(BUF) { _Pragma("unroll") for (int m_ = 0; m_ < 4; ++m_) \
    ai[m_] = *(const i32x4*)(lbase + (BUF)*24576 + baseA + m_*1024); }
#define RDI_B(BUF,NIB) { _Pragma("unroll") for (int n_ = 0; n_ < 2; ++n_) \
    bi[n_] = *(const i32x4*)(lbase + (BUF)*24576 + baseB + ((NIB)+n_)*1024); }
#define MFI_P(NIB) { _Pragma("unroll") for (int m_ = 0; m_ < 4; ++m_) \
  _Pragma("unroll") for (int n_ = 0; n_ < 2; ++n_) \
    acc[m_][(NIB)+n_] = __builtin_amdgcn_mfma_i32_16x16x64_i8(ai[m_], bi[n_], acc[m_][(NIB)+n_], 0, 0, 0); }

template <int MODE, int NDIM, int KDIM>
__global__ __launch_bounds__(512, 2) void gemm4i(
    const signed char* __restrict__ A, const signed char* __restrict__ B,
    signed char* __restrict__ C8, float* __restrict__ Cf,
    const float* __restrict__ sRow, const float* __restrict__ bias)
{
  constexpr int NT = KDIM / 64;
  constexpr int NI = NT / 2;
  __shared__ __align__(16) char lds_raw[49152];
  char* lbase = lds_raw;

  const int tid = threadIdx.x;
  const int lane = tid & 63;
  const int w0 = tid >> 6;
  const int wr = w0 >> 2, wc = w0 & 3;
  const int fr = lane & 15, fq = lane >> 4;

  int gx = gridDim.x;
  int bid = blockIdx.y * gx + blockIdx.x;
  int cpx = (gx * gridDim.y) >> 3;
  int sbid = (bid & 7) * cpx + (bid >> 3);
  const int bn = (sbid % gx) * 256;
  const int bm = (sbid / gx) * 128;

  int rS, cSB;
  INV_SWZ8B(tid * 16, rS, cSB)
  const signed char* sAs = A + (size_t)(bm + rS) * KDIM + cSB;
  const signed char* sBs = B + (size_t)(bn + rS) * KDIM + cSB;

  const int lanep = (fr * 64 + fq * 16) ^ ((fr & 8) << 2);
  const int baseA = wr * 4096 + lanep;
  const int baseB = 8192 + wc * 4096 + lanep;

  i32x4 ai[4], bi[2];
  i32x4 acc[4][4] = {};

  STI_A(0, 0) STI_BH(0, 0, 0) STI_BH(0, 1, 0)
  STI_A(1, 1)
  FENCE;
  asm volatile("s_waitcnt vmcnt(1)" ::: "memory");
  __builtin_amdgcn_s_barrier();
  FENCE;

#pragma unroll 1
  for (int it = 0; it < NI; ++it) {
    const int t1 = 2 * it + 1;
    const int t2 = (2 * it + 2 < NT) ? 2 * it + 2 : NT - 1;
    const int t3 = (2 * it + 3 < NT) ? 2 * it + 3 : NT - 1;
    RDI_A(0) RDI_B(0, 0) STI_BH(1, 0, t1) STI_BH(1, 1, t1)
    PH_MID MFI_P(0) PH_END
    RDI_B(0, 2) STI_A(0, t2)
    PH_MID MFI_P(2) PH_ENDV1
    RDI_A(1) RDI_B(1, 0) STI_BH(0, 0, t2) STI_BH(0, 1, t2)
    PH_MID MFI_P(0) PH_END
    RDI_B(1, 2) STI_A(1, t3)
    PH_MID MFI_P(2) PH_ENDV1
  }

  // ---- epilogue ----
  const int gj0 = bn + wc * 64 + fr;
  const int gi0 = bm + wr * 64 + fq * 4;

  if constexpr (MODE == 0) {
#pragma unroll
    for (int m = 0; m < 4; ++m)
#pragma unroll
      for (int r = 0; r < 4; ++r) {
        const int gi = gi0 + m * 16 + r;
        float sa = sRow[gi];
#pragma unroll
        for (int n = 0; n < 4; ++n)
          C8[(size_t)gi * NDIM + gj0 + n * 16] = q8((float)acc[m][n][r] * sa);
      }
  } else if constexpr (MODE == 1) {
    const float CV = 0.625f / 16129.0f;        // (5/127)*(0.125/127)
#pragma unroll
    for (int m = 0; m < 4; ++m)
#pragma unroll
      for (int r = 0; r < 4; ++r) {
        const int gi = gi0 + m * 16 + r;
        float rb = bias[gi];
#pragma unroll
        for (int n = 0; n < 4; ++n)
          C8[(size_t)gi * NDIM + gj0 + n * 16] =
              q8(((float)acc[m][n][r] * CV + rb) * 15.875f);
      }
  } else {
    const float CO = 1.0f / 16129.0f;          // (8/127)*(0.125/127)
    float cb[4];
#pragma unroll
    for (int n = 0; n < 4; ++n) cb[n] = bias[gj0 + n * 16];
#pragma unroll
    for (int m = 0; m < 4; ++m)
#pragma unroll
      for (int r = 0; r < 4; ++r) {
        const int gi = gi0 + m * 16 + r;
#pragma unroll
        for (int n = 0; n < 4; ++n)
          Cf[(size_t)gi * NDIM + gj0 + n * 16] = (float)acc[m][n][r] * CO + cb[n];
      }
  }
}

// ---------------------------------------------------------------------------
// softmax: f32 A -> d_out, i8 A (q = round(exp*127)) + row scale -> ws
__global__ __launch_bounds__(256) void softmax_rows(const float* __restrict__ S,
                                                    float* __restrict__ Af,
                                                    signed char* __restrict__ Aq,
                                                    float* __restrict__ sRowA) {
  __shared__ float buf[Ltok];
  __shared__ float red[4];
  const int tid = threadIdx.x, lane = tid & 63, w = tid >> 6;
  const float LOG2E = 1.44269504088896f;
  const float* sr = S + (size_t)blockIdx.x * Ltok;
  float lmax = -3.4e38f;
  for (int j = tid * 4; j < Ltok; j += 1024) {
    float4 v = *(const float4*)&sr[j];
    *(float4*)&buf[j] = v;
    lmax = fmaxf(fmaxf(lmax, fmaxf(v.x, v.y)), fmaxf(v.z, v.w));
  }
#pragma unroll
  for (int off = 32; off > 0; off >>= 1) lmax = fmaxf(lmax, __shfl_xor(lmax, off));
  if (lane == 0) red[w] = lmax;
  __syncthreads();
  const float m = fmaxf(fmaxf(red[0], red[1]), fmaxf(red[2], red[3])) * LOG2E;
  __syncthreads();
  float lsum = 0.f;
  for (int j = tid * 4; j < Ltok; j += 1024) {
    lsum += exp2f(buf[j] * LOG2E - m) + exp2f(buf[j + 1] * LOG2E - m) +
            exp2f(buf[j + 2] * LOG2E - m) + exp2f(buf[j + 3] * LOG2E - m);
  }
#pragma unroll
  for (int off = 32; off > 0; off >>= 1) lsum += __shfl_xor(lsum, off);
  if (lane == 0) red[w] = lsum;
  __syncthreads();
  const float inv = 1.0f / (red[0] + red[1] + red[2] + red[3]);
  if (tid == 0) sRowA[blockIdx.x] = inv * (1.0f / 127.0f);
  float* arf = Af + (size_t)blockIdx.x * Ltok;
  signed char* arq = Aq + (size_t)blockIdx.x * Ltok;
  for (int j = tid * 4; j < Ltok; j += 1024) {
    float e0 = exp2f(buf[j] * LOG2E - m);
    float e1 = exp2f(buf[j + 1] * LOG2E - m);
    float e2 = exp2f(buf[j + 2] * LOG2E - m);
    float e3 = exp2f(buf[j + 3] * LOG2E - m);
    float4 aa; aa.x = e0 * inv; aa.y = e1 * inv; aa.z = e2 * inv; aa.w = e3 * inv;
    *(float4*)&arf[j] = aa;
    char4 q;
    q.x = (signed char)(int)rintf(e0 * 127.0f);
    q.y = (signed char)(int)rintf(e1 * 127.0f);
    q.z = (signed char)(int)rintf(e2 * 127.0f);
    q.w = (signed char)(int)rintf(e3 * 127.0f);
    *(char4*)&arq[j] = q;
  }
}

// ---------------------------------------------------------------------------
extern "C" void kernel_launch(void* const* d_in, const int* in_sizes, int n_in,
                              void* d_out, int out_size, void* d_ws, size_t ws_size,
                              hipStream_t stream) {
  const float* tok = (const float*)d_in[0];
  const float* ecc = (const float*)d_in[1];
  const float* Gm  = (const float*)d_in[2];
  const float* Rm  = (const float*)d_in[3];
  const float* Wv  = (const float*)d_in[4];
  const float* bv  = (const float*)d_in[5];
  const float* Wo  = (const float*)d_in[6];
  const float* bo  = (const float*)d_in[7];
  const int*   pos = (const int*)d_in[8];
  const int*   dep = (const int*)d_in[9];

  float* out_f = (float*)d_out;                    // [L][D] f32
  float* A_f   = out_f + (size_t)Ltok * Dm;        // [L][L] f32
  float* S_f   = A_f + (size_t)Ltok * Ltok;        // [L][L] f32

  char* ws = (char*)d_ws;
  size_t off = 0;
  auto alloc = [&](size_t bytes) {
    void* p = ws + off; off = (off + bytes + 255) & ~(size_t)255; return p;
  };
  ushort*      Tbf = (ushort*)alloc((size_t)Ltok * Dm * 2);      // 16 MB
  signed char* Tq  = (signed char*)alloc((size_t)Ltok * Dm);     //  8 MB
  signed char* Wvq = (signed char*)alloc((size_t)Dm * Dm);       //  4 MB
  signed char* Woq = (signed char*)alloc((size_t)Dm * Dm);       //  4 MB
  signed char* Vtq = (signed char*)alloc((size_t)Dm * Ltok);     //  8 MB
  signed char* Aq  = (signed char*)alloc((size_t)Ltok * Ltok);   // 16 MB
  signed char* AVq = (signed char*)alloc((size_t)Ltok * Dm);     //  8 MB
  float4* tokf4 = (float4*)alloc(Ltok * 16);
  float*  sGR  = (float*)alloc(64 * 4);
  float*  sRowA = (float*)alloc(Ltok * 4);

  prep_tokens<<<Ltok, 256, 0, stream>>>(tok, ecc, pos, dep, Tbf, Tq, tokf4);
  cast_f32_i8<<<(Dm * Dm) / 1024, 256, 0, stream>>>(Wv, Wvq, Dm * Dm);
  cast_f32_i8<<<(Dm * Dm) / 1024, 256, 0, stream>>>(Wo, Woq, Dm * Dm);
  small_prep<<<1, 64, 0, stream>>>(Gm, Rm, sGR);

  // scores = c_ij * (T @ T^T) -> f32   (gemm8, 256 blocks, proven)
  gemm8<Ltok, Dm><<<dim3(Ltok / 256, Ltok / 256), 512, 0, stream>>>(
      Tbf, Tbf, S_f, tokf4, sGR);
  // A = softmax(scores): f32 -> d_out, i8 + row scale -> ws
  softmax_rows<<<Ltok, 256, 0, stream>>>(S_f, A_f, Aq, sRowA);

  // V^T[d][l] i8 = quant(Wvq . Tq * CV + bv)   (grid 16x16 = 256 blocks)
  gemm4i<1, Ltok, Dm><<<dim3(Ltok / 256, Dm / 128), 512, 0, stream>>>(
      Wvq, Tq, Vtq, nullptr, nullptr, bv);

  // AV i8 = quant(Aq @ Vtq * sRow)   (grid 8x32 = 256 blocks)
  gemm4i<0, Dm, Ltok><<<dim3(Dm / 256, Ltok / 128), 512, 0, stream>>>(
      Aq, Vtq, AVq, nullptr, sRowA, nullptr);

  // out f32 = AVq @ Woq * CO + bo   (grid 8x32 = 256 blocks)
  gemm4i<2, Dm, Dm><<<dim3(Dm / 256, Ltok / 128), 512, 0, stream>>>(
      AVq, Woq, nullptr, out_f, nullptr, bo);
}

// Round 14
// 187.539 us; speedup vs baseline: 1.4218x; 1.1324x over previous
//
#include <hip/hip_runtime.h>
#include <cstdint>

#define Ltok 4096
#define Dm   2048

typedef __attribute__((ext_vector_type(4))) float f32x4;
typedef __attribute__((ext_vector_type(4))) int   i32x4;

static __device__ __forceinline__ ushort f2bf(float x) {
  union { float f; uint32_t u; } v; v.f = x;
  uint32_t r = v.u + 0x7FFFu + ((v.u >> 16) & 1u);
  return (ushort)(r >> 16);
}
static __device__ __forceinline__ signed char q8(float x) {
  x = fminf(fmaxf(x, -127.0f), 127.0f);
  return (signed char)(int)rintf(x);
}

typedef __attribute__((address_space(1))) void gv_t;
typedef __attribute__((address_space(3))) void lv_t;
static __device__ __forceinline__ void lds_load16(const void* g, void* l) {
  __builtin_amdgcn_global_load_lds((gv_t*)g, (lv_t*)l, 16, 0, 0);
}

// ---------------------------------------------------------------------------
// prep: row norm + i8 cast (scale 127/5) + packed per-token params
__global__ __launch_bounds__(256) void prep_tokens(const float* __restrict__ T,
                                                   const float* __restrict__ ecc,
                                                   const int* __restrict__ pos,
                                                   const int* __restrict__ dep,
                                                   signed char* __restrict__ Tq,
                                                   float4* __restrict__ tokf4) {
  __shared__ float red[4];
  const int tid = threadIdx.x, lane = tid & 63, w = tid >> 6;
  const int row = blockIdx.x;
  const float* rp = T + (size_t)row * Dm;
  signed char* oq = Tq + (size_t)row * Dm;
  float ss = 0.f;
  for (int j = tid * 4; j < Dm; j += 1024) {
    float4 v = *(const float4*)&rp[j];
    ss += v.x * v.x + v.y * v.y + v.z * v.z + v.w * v.w;
    char4 q; q.x = q8(v.x * 25.4f); q.y = q8(v.y * 25.4f);
    q.z = q8(v.z * 25.4f); q.w = q8(v.w * 25.4f);
    *(char4*)&oq[j] = q;
  }
#pragma unroll
  for (int off = 32; off > 0; off >>= 1) ss += __shfl_xor(ss, off);
  if (lane == 0) red[w] = ss;
  __syncthreads();
  if (tid == 0) {
    float n = sqrtf(red[0] + red[1] + red[2] + red[3]);
    int d = dep[row];
    float4 t;
    t.x = n / (n + 1e-8f);
    t.y = ecc[row];
    t.z = (d <= 0) ? 1.0f : (d == 1 ? 3.0f : 9.0f);
    t.w = (float)pos[row];
    tokf4[row] = t;
  }
}

// weights f32 -> i8 at scale 127/0.125 = 1016
__global__ __launch_bounds__(256) void cast_f32_i8(const float* __restrict__ in,
                                                   signed char* __restrict__ out, int n) {
  int i = (blockIdx.x * 256 + threadIdx.x) * 4;
  if (i + 3 < n) {
    float4 v = *(const float4*)&in[i];
    char4 q; q.x = q8(v.x * 1016.0f); q.y = q8(v.y * 1016.0f);
    q.z = q8(v.z * 1016.0f); q.w = q8(v.w * 1016.0f);
    *(char4*)&out[i] = q;
  }
}

__global__ void small_prep(const float* __restrict__ G, const float* __restrict__ R,
                           float* __restrict__ sGR) {
  int tid = threadIdx.x;
  if (tid < 64) {
    float g = 1.0f / (1.0f + expf(-G[tid]));
    float r = 1.0f / (1.0f + expf(-R[tid]));
    sGR[tid] = g * r;
  }
}

// ---------------------------------------------------------------------------
#define FENCE asm volatile("" ::: "memory")
#define PH_MID { FENCE; __builtin_amdgcn_s_barrier(); __builtin_amdgcn_s_setprio(1); }
#define PH_END { __builtin_amdgcn_s_setprio(0); FENCE; __builtin_amdgcn_s_barrier(); FENCE; }
#define PH_ENDV1 { __builtin_amdgcn_s_setprio(0); FENCE; \
                  asm volatile("s_waitcnt vmcnt(1)" ::: "memory"); \
                  __builtin_amdgcn_s_barrier(); FENCE; }

// inverse swizzle within an 8KB unit, byte-addressed ([128 rows][64 bytes])
#define INV_SWZ8B(P, ROW, COLB) { \
  int s_ = (P) >> 10, ww_ = (P) & 1023; \
  ww_ ^= ((ww_ >> 9) & 1) << 5; \
  ROW = (s_ << 4) + (ww_ >> 6); \
  COLB = ww_ & 63; }

// ===========================================================================
// gemm4i: i8 GEMM, 128x256 tile, BK=64 bytes, 8 waves (2Mx4N), 4-phase,
// 48KB LDS double-buffer, counted vmcnt(1) drains.  (round-11-proven loop)
// MODE 0: AV     -> i8  (q = rint(acc * sRow[gi]))
// MODE 1: V      -> i8  (q = rint((acc*CV + bias[gi]) * 127/8))
// MODE 2: out    -> f32 (acc*CO + bias[gj])
// MODE 3: scores -> f32 (acc*S2 * c_ij, zero diag)
#define STI_A(BUF,KT) \
  lds_load16(sAs + (size_t)(KT)*64, lbase + (BUF)*24576 + tid*16);
#define STI_BH(BUF,H,KT) \
  lds_load16(sBs + (size_t)(H)*128*KDIM + (size_t)(KT)*64, lbase + (BUF)*24576 + 8192 + (H)*8192 + tid*16);
#define RDI_A(BUF) { _Pragma("unroll") for (int m_ = 0; m_ < 4; ++m_) \
    ai[m_] = *(const i32x4*)(lbase + (BUF)*24576 + baseA + m_*1024); }
#define RDI_B(BUF,NIB) { _Pragma("unroll") for (int n_ = 0; n_ < 2; ++n_) \
    bi[n_] = *(const i32x4*)(lbase + (BUF)*24576 + baseB + ((NIB)+n_)*1024); }
#define MFI_P(NIB) { _Pragma("unroll") for (int m_ = 0; m_ < 4; ++m_) \
  _Pragma("unroll") for (int n_ = 0; n_ < 2; ++n_) \
    acc[m_][(NIB)+n_] = __builtin_amdgcn_mfma_i32_16x16x64_i8(ai[m_], bi[n_], acc[m_][(NIB)+n_], 0, 0, 0); }

template <int MODE, int NDIM, int KDIM>
__global__ __launch_bounds__(512, 2) void gemm4i(
    const signed char* __restrict__ A, const signed char* __restrict__ B,
    signed char* __restrict__ C8, float* __restrict__ Cf,
    const float* __restrict__ sRow, const float* __restrict__ bias,
    const float4* __restrict__ tokf4, const float* __restrict__ sGR)
{
  constexpr int NT = KDIM / 64;
  constexpr int NI = NT / 2;
  __shared__ __align__(16) char lds_raw[49152];
  char* lbase = lds_raw;

  const int tid = threadIdx.x;
  const int lane = tid & 63;
  const int w0 = tid >> 6;
  const int wr = w0 >> 2, wc = w0 & 3;
  const int fr = lane & 15, fq = lane >> 4;

  int gx = gridDim.x;
  int bid = blockIdx.y * gx + blockIdx.x;
  int cpx = (gx * gridDim.y) >> 3;
  int sbid = (bid & 7) * cpx + (bid >> 3);
  const int bn = (sbid % gx) * 256;
  const int bm = (sbid / gx) * 128;

  int rS, cSB;
  INV_SWZ8B(tid * 16, rS, cSB)
  const signed char* sAs = A + (size_t)(bm + rS) * KDIM + cSB;
  const signed char* sBs = B + (size_t)(bn + rS) * KDIM + cSB;

  const int lanep = (fr * 64 + fq * 16) ^ ((fr & 8) << 2);
  const int baseA = wr * 4096 + lanep;
  const int baseB = 8192 + wc * 4096 + lanep;

  i32x4 ai[4], bi[2];
  i32x4 acc[4][4] = {};

  STI_A(0, 0) STI_BH(0, 0, 0) STI_BH(0, 1, 0)
  STI_A(1, 1)
  FENCE;
  asm volatile("s_waitcnt vmcnt(1)" ::: "memory");
  __builtin_amdgcn_s_barrier();
  FENCE;

#pragma unroll 1
  for (int it = 0; it < NI; ++it) {
    const int t1 = 2 * it + 1;
    const int t2 = (2 * it + 2 < NT) ? 2 * it + 2 : NT - 1;
    const int t3 = (2 * it + 3 < NT) ? 2 * it + 3 : NT - 1;
    RDI_A(0) RDI_B(0, 0) STI_BH(1, 0, t1) STI_BH(1, 1, t1)
    PH_MID MFI_P(0) PH_END
    RDI_B(0, 2) STI_A(0, t2)
    PH_MID MFI_P(2) PH_ENDV1
    RDI_A(1) RDI_B(1, 0) STI_BH(0, 0, t2) STI_BH(0, 1, t2)
    PH_MID MFI_P(0) PH_END
    RDI_B(1, 2) STI_A(1, t3)
    PH_MID MFI_P(2) PH_ENDV1
  }

  // ---- epilogue ----
  const int gj0 = bn + wc * 64 + fr;
  const int gi0 = bm + wr * 64 + fq * 4;

  if constexpr (MODE == 0) {
#pragma unroll
    for (int m = 0; m < 4; ++m)
#pragma unroll
      for (int r = 0; r < 4; ++r) {
        const int gi = gi0 + m * 16 + r;
        float sa = sRow[gi];
#pragma unroll
        for (int n = 0; n < 4; ++n)
          C8[(size_t)gi * NDIM + gj0 + n * 16] = q8((float)acc[m][n][r] * sa);
      }
  } else if constexpr (MODE == 1) {
    const float CV = 0.625f / 16129.0f;        // (5/127)*(0.125/127)
#pragma unroll
    for (int m = 0; m < 4; ++m)
#pragma unroll
      for (int r = 0; r < 4; ++r) {
        const int gi = gi0 + m * 16 + r;
        float rb = bias[gi];
#pragma unroll
        for (int n = 0; n < 4; ++n)
          C8[(size_t)gi * NDIM + gj0 + n * 16] =
              q8(((float)acc[m][n][r] * CV + rb) * 15.875f);
      }
  } else if constexpr (MODE == 2) {
    const float CO = 1.0f / 16129.0f;          // (8/127)*(0.125/127)
    float cb[4];
#pragma unroll
    for (int n = 0; n < 4; ++n) cb[n] = bias[gj0 + n * 16];
#pragma unroll
    for (int m = 0; m < 4; ++m)
#pragma unroll
      for (int r = 0; r < 4; ++r) {
        const int gi = gi0 + m * 16 + r;
#pragma unroll
        for (int n = 0; n < 4; ++n)
          Cf[(size_t)gi * NDIM + gj0 + n * 16] = (float)acc[m][n][r] * CO + cb[n];
      }
  } else {
    // MODE 3: scores.  dot = acc * (5/127)^2; x = dot * c_ij; zero diag.
    const float S2 = 25.0f / 16129.0f;
    float4 cj[4];
#pragma unroll
    for (int n = 0; n < 4; ++n) cj[n] = tokf4[gj0 + n * 16];
#pragma unroll
    for (int m = 0; m < 4; ++m) {
#pragma unroll
      for (int r = 0; r < 4; ++r) {
        const int gi = gi0 + m * 16 + r;
        float4 ci = tokf4[gi];
#pragma unroll
        for (int n = 0; n < 4; ++n) {
          const int gj = gj0 + n * 16;
          float x = (float)acc[m][n][r] * S2;
          float rr = fabsf(ci.z - cj[n].z) + 1.0f;
          int pi = (int)ci.w, pj = (int)cj[n].w;
          float c = sGR[pi * 8 + pj] * (1.0f - ci.y * cj[n].y) *
                    (ci.x * cj[n].x) * __builtin_amdgcn_rcpf(rr * rr);
          x *= c;
          if (gi == gj) x = 0.0f;
          Cf[(size_t)gi * NDIM + gj] = x;
        }
      }
    }
  }
}

// ---------------------------------------------------------------------------
// softmax: f32 A -> d_out, i8 A (q = round(exp*127)) + row scale -> ws
__global__ __launch_bounds__(256) void softmax_rows(const float* __restrict__ S,
                                                    float* __restrict__ Af,
                                                    signed char* __restrict__ Aq,
                                                    float* __restrict__ sRowA) {
  __shared__ float buf[Ltok];
  __shared__ float red[4];
  const int tid = threadIdx.x, lane = tid & 63, w = tid >> 6;
  const float LOG2E = 1.44269504088896f;
  const float* sr = S + (size_t)blockIdx.x * Ltok;
  float lmax = -3.4e38f;
  for (int j = tid * 4; j < Ltok; j += 1024) {
    float4 v = *(const float4*)&sr[j];
    *(float4*)&buf[j] = v;
    lmax = fmaxf(fmaxf(lmax, fmaxf(v.x, v.y)), fmaxf(v.z, v.w));
  }
#pragma unroll
  for (int off = 32; off > 0; off >>= 1) lmax = fmaxf(lmax, __shfl_xor(lmax, off));
  if (lane == 0) red[w] = lmax;
  __syncthreads();
  const float m = fmaxf(fmaxf(red[0], red[1]), fmaxf(red[2], red[3])) * LOG2E;
  __syncthreads();
  float lsum = 0.f;
  for (int j = tid * 4; j < Ltok; j += 1024) {
    lsum += exp2f(buf[j] * LOG2E - m) + exp2f(buf[j + 1] * LOG2E - m) +
            exp2f(buf[j + 2] * LOG2E - m) + exp2f(buf[j + 3] * LOG2E - m);
  }
#pragma unroll
  for (int off = 32; off > 0; off >>= 1) lsum += __shfl_xor(lsum, off);
  if (lane == 0) red[w] = lsum;
  __syncthreads();
  const float inv = 1.0f / (red[0] + red[1] + red[2] + red[3]);
  if (tid == 0) sRowA[blockIdx.x] = inv * (1.0f / 127.0f);
  float* arf = Af + (size_t)blockIdx.x * Ltok;
  signed char* arq = Aq + (size_t)blockIdx.x * Ltok;
  for (int j = tid * 4; j < Ltok; j += 1024) {
    float e0 = exp2f(buf[j] * LOG2E - m);
    float e1 = exp2f(buf[j + 1] * LOG2E - m);
    float e2 = exp2f(buf[j + 2] * LOG2E - m);
    float e3 = exp2f(buf[j + 3] * LOG2E - m);
    float4 aa; aa.x = e0 * inv; aa.y = e1 * inv; aa.z = e2 * inv; aa.w = e3 * inv;
    *(float4*)&arf[j] = aa;
    char4 q;
    q.x = (signed char)(int)rintf(e0 * 127.0f);
    q.y = (signed char)(int)rintf(e1 * 127.0f);
    q.z = (signed char)(int)rintf(e2 * 127.0f);
    q.w = (signed char)(int)rintf(e3 * 127.0f);
    *(char4*)&arq[j] = q;
  }
}

// ---------------------------------------------------------------------------
extern "C" void kernel_launch(void* const* d_in, const int* in_sizes, int n_in,
                              void* d_out, int out_size, void* d_ws, size_t ws_size,
                              hipStream_t stream) {
  const float* tok = (const float*)d_in[0];
  const float* ecc = (const float*)d_in[1];
  const float* Gm  = (const float*)d_in[2];
  const float* Rm  = (const float*)d_in[3];
  const float* Wv  = (const float*)d_in[4];
  const float* bv  = (const float*)d_in[5];
  const float* Wo  = (const float*)d_in[6];
  const float* bo  = (const float*)d_in[7];
  const int*   pos = (const int*)d_in[8];
  const int*   dep = (const int*)d_in[9];

  float* out_f = (float*)d_out;                    // [L][D] f32
  float* A_f   = out_f + (size_t)Ltok * Dm;        // [L][L] f32
  float* S_f   = A_f + (size_t)Ltok * Ltok;        // [L][L] f32

  char* ws = (char*)d_ws;
  size_t off = 0;
  auto alloc = [&](size_t bytes) {
    void* p = ws + off; off = (off + bytes + 255) & ~(size_t)255; return p;
  };
  signed char* Tq  = (signed char*)alloc((size_t)Ltok * Dm);     //  8 MB
  signed char* Wvq = (signed char*)alloc((size_t)Dm * Dm);       //  4 MB
  signed char* Woq = (signed char*)alloc((size_t)Dm * Dm);       //  4 MB
  signed char* Vtq = (signed char*)alloc((size_t)Dm * Ltok);     //  8 MB
  signed char* Aq  = (signed char*)alloc((size_t)Ltok * Ltok);   // 16 MB
  signed char* AVq = (signed char*)alloc((size_t)Ltok * Dm);     //  8 MB
  float4* tokf4 = (float4*)alloc(Ltok * 16);
  float*  sGR  = (float*)alloc(64 * 4);
  float*  sRowA = (float*)alloc(Ltok * 4);

  prep_tokens<<<Ltok, 256, 0, stream>>>(tok, ecc, pos, dep, Tq, tokf4);
  cast_f32_i8<<<(Dm * Dm) / 1024, 256, 0, stream>>>(Wv, Wvq, Dm * Dm);
  cast_f32_i8<<<(Dm * Dm) / 1024, 256, 0, stream>>>(Wo, Woq, Dm * Dm);
  small_prep<<<1, 64, 0, stream>>>(Gm, Rm, sGR);

  // scores f32 = (Tq . Tq) * S2 * c_ij   (i8 GEMM, grid 16x32 = 512 blocks)
  gemm4i<3, Ltok, Dm><<<dim3(Ltok / 256, Ltok / 128), 512, 0, stream>>>(
      Tq, Tq, nullptr, S_f, nullptr, nullptr, tokf4, sGR);
  // A = softmax(scores): f32 -> d_out, i8 + row scale -> ws
  softmax_rows<<<Ltok, 256, 0, stream>>>(S_f, A_f, Aq, sRowA);

  // V^T[d][l] i8 = quant(Wvq . Tq * CV + bv)   (grid 16x16 = 256 blocks)
  gemm4i<1, Ltok, Dm><<<dim3(Ltok / 256, Dm / 128), 512, 0, stream>>>(
      Wvq, Tq, Vtq, nullptr, nullptr, bv, nullptr, nullptr);

  // AV i8 = quant(Aq @ Vtq * sRow)   (grid 8x32 = 256 blocks)
  gemm4i<0, Dm, Ltok><<<dim3(Dm / 256, Ltok / 128), 512, 0, stream>>>(
      Aq, Vtq, AVq, nullptr, sRowA, nullptr, nullptr, nullptr);

  // out f32 = AVq @ Woq * CO + bo   (grid 8x32 = 256 blocks)
  gemm4i<2, Dm, Dm><<<dim3(Dm / 256, Ltok / 128), 512, 0, stream>>>(
      AVq, Woq, nullptr, out_f, nullptr, bo, nullptr, nullptr);
}

// Round 15
// 183.140 us; speedup vs baseline: 1.4559x; 1.0240x over previous
//
#include <hip/hip_runtime.h>
#include <cstdint>

#define Ltok 4096
#define Dm   2048

typedef __attribute__((ext_vector_type(4))) float f32x4;
typedef __attribute__((ext_vector_type(4))) int   i32x4;

static __device__ __forceinline__ signed char q8(float x) {
  x = fminf(fmaxf(x, -127.0f), 127.0f);
  return (signed char)(int)rintf(x);
}

typedef __attribute__((address_space(1))) void gv_t;
typedef __attribute__((address_space(3))) void lv_t;
static __device__ __forceinline__ void lds_load16(const void* g, void* l) {
  __builtin_amdgcn_global_load_lds((gv_t*)g, (lv_t*)l, 16, 0, 0);
}

// ---------------------------------------------------------------------------
// prep: row norm + i8 cast (scale 127/5) + packed per-token params
__global__ __launch_bounds__(256) void prep_tokens(const float* __restrict__ T,
                                                   const float* __restrict__ ecc,
                                                   const int* __restrict__ pos,
                                                   const int* __restrict__ dep,
                                                   signed char* __restrict__ Tq,
                                                   float4* __restrict__ tokf4) {
  __shared__ float red[4];
  const int tid = threadIdx.x, lane = tid & 63, w = tid >> 6;
  const int row = blockIdx.x;
  const float* rp = T + (size_t)row * Dm;
  signed char* oq = Tq + (size_t)row * Dm;
  float ss = 0.f;
  for (int j = tid * 4; j < Dm; j += 1024) {
    float4 v = *(const float4*)&rp[j];
    ss += v.x * v.x + v.y * v.y + v.z * v.z + v.w * v.w;
    char4 q; q.x = q8(v.x * 25.4f); q.y = q8(v.y * 25.4f);
    q.z = q8(v.z * 25.4f); q.w = q8(v.w * 25.4f);
    *(char4*)&oq[j] = q;
  }
#pragma unroll
  for (int off = 32; off > 0; off >>= 1) ss += __shfl_xor(ss, off);
  if (lane == 0) red[w] = ss;
  __syncthreads();
  if (tid == 0) {
    float n = sqrtf(red[0] + red[1] + red[2] + red[3]);
    int d = dep[row];
    float4 t;
    t.x = n / (n + 1e-8f);
    t.y = ecc[row];
    t.z = (d <= 0) ? 1.0f : (d == 1 ? 3.0f : 9.0f);
    t.w = (float)pos[row];
    tokf4[row] = t;
  }
}

// weights f32 -> i8 at scale 127/0.125 = 1016
__global__ __launch_bounds__(256) void cast_f32_i8(const float* __restrict__ in,
                                                   signed char* __restrict__ out, int n) {
  int i = (blockIdx.x * 256 + threadIdx.x) * 4;
  if (i + 3 < n) {
    float4 v = *(const float4*)&in[i];
    char4 q; q.x = q8(v.x * 1016.0f); q.y = q8(v.y * 1016.0f);
    q.z = q8(v.z * 1016.0f); q.w = q8(v.w * 1016.0f);
    *(char4*)&out[i] = q;
  }
}

__global__ void small_prep(const float* __restrict__ G, const float* __restrict__ R,
                           float* __restrict__ sGR) {
  int tid = threadIdx.x;
  if (tid < 64) {
    float g = 1.0f / (1.0f + expf(-G[tid]));
    float r = 1.0f / (1.0f + expf(-R[tid]));
    sGR[tid] = g * r;
  }
}

// ---------------------------------------------------------------------------
#define FENCE asm volatile("" ::: "memory")
#define PH_MID { FENCE; __builtin_amdgcn_s_barrier(); __builtin_amdgcn_s_setprio(1); }
#define PH_END { __builtin_amdgcn_s_setprio(0); FENCE; __builtin_amdgcn_s_barrier(); FENCE; }
#define PH_ENDV1 { __builtin_amdgcn_s_setprio(0); FENCE; \
                  asm volatile("s_waitcnt vmcnt(1)" ::: "memory"); \
                  __builtin_amdgcn_s_barrier(); FENCE; }
#define PH_ENDV2 { __builtin_amdgcn_s_setprio(0); FENCE; \
                  asm volatile("s_waitcnt vmcnt(2)" ::: "memory"); \
                  __builtin_amdgcn_s_barrier(); FENCE; }

// inverse swizzle within an 8KB unit, byte-addressed ([128 rows][64 bytes])
#define INV_SWZ8B(P, ROW, COLB) { \
  int s_ = (P) >> 10, ww_ = (P) & 1023; \
  ww_ ^= ((ww_ >> 9) & 1) << 5; \
  ROW = (s_ << 4) + (ww_ >> 6); \
  COLB = ww_ & 63; }

// ===========================================================================
// gemm8i: i8 scores GEMM, 256x256 tile, BK=64 bytes, 8 waves (2Mx4N,
// per-wave 128x64), 4-phase, 64KB LDS double-buffer.
// LDS buf (32768B stride): A [256r][64B] = 2x8KB units @0,@8192;
//                          B [256r][64B] = 2x8KB units @16384,@24576.
// Loads/phase: P1:2 (buf1.B<-t1) P2:2 (buf0.A<-t2) P3:2 (buf0.B<-t2)
//              P4:2 (buf1.A<-t3).  Drains vmcnt(2) @P2-end, @P4-end.
// Stages strictly after region's last reader: A read fully in P1/P3 quad,
// B n0-1 in P1/P3, n2-3 in P2/P4 (same discipline as proven gemm4i).
#define STI8_A(BUF,H,KT) \
  lds_load16(sAs + (size_t)(H)*128*Dm + (size_t)(KT)*64, lbase + (BUF)*32768 + (H)*8192 + tid*16);
#define STI8_B(BUF,H,KT) \
  lds_load16(sBs + (size_t)(H)*128*Dm + (size_t)(KT)*64, lbase + (BUF)*32768 + 16384 + (H)*8192 + tid*16);
#define RDI8_A(BUF) { _Pragma("unroll") for (int m_ = 0; m_ < 8; ++m_) \
    ai[m_] = *(const i32x4*)(lbase + (BUF)*32768 + baseA + m_*1024); }
#define RDI8_B(BUF,NIB) { _Pragma("unroll") for (int n_ = 0; n_ < 2; ++n_) \
    bi[n_] = *(const i32x4*)(lbase + (BUF)*32768 + baseB + ((NIB)+n_)*1024); }
#define MFI8_P(NIB) { _Pragma("unroll") for (int m_ = 0; m_ < 8; ++m_) \
  _Pragma("unroll") for (int n_ = 0; n_ < 2; ++n_) \
    acc[m_][(NIB)+n_] = __builtin_amdgcn_mfma_i32_16x16x64_i8(ai[m_], bi[n_], acc[m_][(NIB)+n_], 0, 0, 0); }

__global__ __launch_bounds__(512, 2) void gemm8i(
    const signed char* __restrict__ A,
    float* __restrict__ Cf,
    const float4* __restrict__ tokf4, const float* __restrict__ sGR)
{
  constexpr int NT = Dm / 64;
  constexpr int NI = NT / 2;
  __shared__ __align__(16) char lds_raw[65536];
  char* lbase = lds_raw;

  const int tid = threadIdx.x;
  const int lane = tid & 63;
  const int w0 = tid >> 6;
  const int wr = w0 >> 2, wc = w0 & 3;
  const int fr = lane & 15, fq = lane >> 4;

  int gx = gridDim.x;
  int bid = blockIdx.y * gx + blockIdx.x;
  int cpx = (gx * gridDim.y) >> 3;
  int sbid = (bid & 7) * cpx + (bid >> 3);
  const int bn = (sbid % gx) * 256;
  const int bm = (sbid / gx) * 256;

  int rS, cSB;
  INV_SWZ8B(tid * 16, rS, cSB)
  const signed char* sAs = A + (size_t)(bm + rS) * Dm + cSB;
  const signed char* sBs = A + (size_t)(bn + rS) * Dm + cSB;

  const int lanep = (fr * 64 + fq * 16) ^ ((fr & 8) << 2);
  const int baseA = wr * 8192 + lanep;
  const int baseB = 16384 + (wc >> 1) * 8192 + (wc & 1) * 4096 + lanep;

  i32x4 ai[8], bi[2];
  i32x4 acc[8][4] = {};

  // prologue: buf0 <- t0 (A both halves + B both halves), buf1.A <- t1
  STI8_A(0, 0, 0) STI8_A(0, 1, 0) STI8_B(0, 0, 0) STI8_B(0, 1, 0)
  STI8_A(1, 0, 1) STI8_A(1, 1, 1)
  FENCE;
  asm volatile("s_waitcnt vmcnt(2)" ::: "memory");
  __builtin_amdgcn_s_barrier();
  FENCE;

#pragma unroll 1
  for (int it = 0; it < NI; ++it) {
    const int t1 = 2 * it + 1;
    const int t2 = (2 * it + 2 < NT) ? 2 * it + 2 : NT - 1;
    const int t3 = (2 * it + 3 < NT) ? 2 * it + 3 : NT - 1;
    // P1: rd buf0 {A m0-7, B n0-1}; stage buf1.B <- t1 (dead since prev P4)
    RDI8_A(0) RDI8_B(0, 0) STI8_B(1, 0, t1) STI8_B(1, 1, t1)
    PH_MID MFI8_P(0) PH_END
    // P2: rd buf0 B n2-3; stage buf0.A <- t2 (A read fully in P1); drain buf1
    RDI8_B(0, 2) STI8_A(0, 0, t2) STI8_A(0, 1, t2)
    PH_MID MFI8_P(2) PH_ENDV2
    // P3: rd buf1 {A, B n0-1}; stage buf0.B <- t2 (B read fully by P2)
    RDI8_A(1) RDI8_B(1, 0) STI8_B(0, 0, t2) STI8_B(0, 1, t2)
    PH_MID MFI8_P(0) PH_END
    // P4: rd buf1 B n2-3; stage buf1.A <- t3 (A read fully in P3); drain buf0
    RDI8_B(1, 2) STI8_A(1, 0, t3) STI8_A(1, 1, t3)
    PH_MID MFI8_P(2) PH_ENDV2
  }

  // ---- epilogue: scores (identical per-element math to round-14 MODE 3) ----
  const float S2 = 25.0f / 16129.0f;
  const int gj0 = bn + wc * 64 + fr;
  const int gi0 = bm + wr * 128 + fq * 4;
  float4 cj[4];
#pragma unroll
  for (int n = 0; n < 4; ++n) cj[n] = tokf4[gj0 + n * 16];
#pragma unroll
  for (int m = 0; m < 8; ++m) {
#pragma unroll
    for (int r = 0; r < 4; ++r) {
      const int gi = gi0 + m * 16 + r;
      float4 ci = tokf4[gi];
#pragma unroll
      for (int n = 0; n < 4; ++n) {
        const int gj = gj0 + n * 16;
        float x = (float)acc[m][n][r] * S2;
        float rr = fabsf(ci.z - cj[n].z) + 1.0f;
        int pi = (int)ci.w, pj = (int)cj[n].w;
        float c = sGR[pi * 8 + pj] * (1.0f - ci.y * cj[n].y) *
                  (ci.x * cj[n].x) * __builtin_amdgcn_rcpf(rr * rr);
        x *= c;
        if (gi == gj) x = 0.0f;
        Cf[(size_t)gi * Ltok + gj] = x;
      }
    }
  }
}

// ===========================================================================
// gemm4i: i8 GEMM, 128x256 tile, BK=64 bytes, 8 waves (2Mx4N), 4-phase,
// 48KB LDS double-buffer, counted vmcnt(1) drains.  (round-11-proven, FROZEN)
// MODE 0: AV -> i8   MODE 1: V -> i8   MODE 2: out -> f32
#define STI_A(BUF,KT) \
  lds_load16(sAs + (size_t)(KT)*64, lbase + (BUF)*24576 + tid*16);
#define STI_BH(BUF,H,KT) \
  lds_load16(sBs + (size_t)(H)*128*KDIM + (size_t)(KT)*64, lbase + (BUF)*24576 + 8192 + (H)*8192 + tid*16);
#define RDI_A(BUF) { _Pragma("unroll") for (int m_ = 0; m_ < 4; ++m_) \
    ai[m_] = *(const i32x4*)(lbase + (BUF)*24576 + baseA + m_*1024); }
#define RDI_B(BUF,NIB) { _Pragma("unroll") for (int n_ = 0; n_ < 2; ++n_) \
    bi[n_] = *(const i32x4*)(lbase + (BUF)*24576 + baseB + ((NIB)+n_)*1024); }
#define MFI_P(NIB) { _Pragma("unroll") for (int m_ = 0; m_ < 4; ++m_) \
  _Pragma("unroll") for (int n_ = 0; n_ < 2; ++n_) \
    acc[m_][(NIB)+n_] = __builtin_amdgcn_mfma_i32_16x16x64_i8(ai[m_], bi[n_], acc[m_][(NIB)+n_], 0, 0, 0); }

template <int MODE, int NDIM, int KDIM>
__global__ __launch_bounds__(512, 2) void gemm4i(
    const signed char* __restrict__ A, const signed char* __restrict__ B,
    signed char* __restrict__ C8, float* __restrict__ Cf,
    const float* __restrict__ sRow, const float* __restrict__ bias)
{
  constexpr int NT = KDIM / 64;
  constexpr int NI = NT / 2;
  __shared__ __align__(16) char lds_raw[49152];
  char* lbase = lds_raw;

  const int tid = threadIdx.x;
  const int lane = tid & 63;
  const int w0 = tid >> 6;
  const int wr = w0 >> 2, wc = w0 & 3;
  const int fr = lane & 15, fq = lane >> 4;

  int gx = gridDim.x;
  int bid = blockIdx.y * gx + blockIdx.x;
  int cpx = (gx * gridDim.y) >> 3;
  int sbid = (bid & 7) * cpx + (bid >> 3);
  const int bn = (sbid % gx) * 256;
  const int bm = (sbid / gx) * 128;

  int rS, cSB;
  INV_SWZ8B(tid * 16, rS, cSB)
  const signed char* sAs = A + (size_t)(bm + rS) * KDIM + cSB;
  const signed char* sBs = B + (size_t)(bn + rS) * KDIM + cSB;

  const int lanep = (fr * 64 + fq * 16) ^ ((fr & 8) << 2);
  const int baseA = wr * 4096 + lanep;
  const int baseB = 8192 + wc * 4096 + lanep;

  i32x4 ai[4], bi[2];
  i32x4 acc[4][4] = {};

  STI_A(0, 0) STI_BH(0, 0, 0) STI_BH(0, 1, 0)
  STI_A(1, 1)
  FENCE;
  asm volatile("s_waitcnt vmcnt(1)" ::: "memory");
  __builtin_amdgcn_s_barrier();
  FENCE;

#pragma unroll 1
  for (int it = 0; it < NI; ++it) {
    const int t1 = 2 * it + 1;
    const int t2 = (2 * it + 2 < NT) ? 2 * it + 2 : NT - 1;
    const int t3 = (2 * it + 3 < NT) ? 2 * it + 3 : NT - 1;
    RDI_A(0) RDI_B(0, 0) STI_BH(1, 0, t1) STI_BH(1, 1, t1)
    PH_MID MFI_P(0) PH_END
    RDI_B(0, 2) STI_A(0, t2)
    PH_MID MFI_P(2) PH_ENDV1
    RDI_A(1) RDI_B(1, 0) STI_BH(0, 0, t2) STI_BH(0, 1, t2)
    PH_MID MFI_P(0) PH_END
    RDI_B(1, 2) STI_A(1, t3)
    PH_MID MFI_P(2) PH_ENDV1
  }

  // ---- epilogue ----
  const int gj0 = bn + wc * 64 + fr;
  const int gi0 = bm + wr * 64 + fq * 4;

  if constexpr (MODE == 0) {
#pragma unroll
    for (int m = 0; m < 4; ++m)
#pragma unroll
      for (int r = 0; r < 4; ++r) {
        const int gi = gi0 + m * 16 + r;
        float sa = sRow[gi];
#pragma unroll
        for (int n = 0; n < 4; ++n)
          C8[(size_t)gi * NDIM + gj0 + n * 16] = q8((float)acc[m][n][r] * sa);
      }
  } else if constexpr (MODE == 1) {
    const float CV = 0.625f / 16129.0f;        // (5/127)*(0.125/127)
#pragma unroll
    for (int m = 0; m < 4; ++m)
#pragma unroll
      for (int r = 0; r < 4; ++r) {
        const int gi = gi0 + m * 16 + r;
        float rb = bias[gi];
#pragma unroll
        for (int n = 0; n < 4; ++n)
          C8[(size_t)gi * NDIM + gj0 + n * 16] =
              q8(((float)acc[m][n][r] * CV + rb) * 15.875f);
      }
  } else {
    const float CO = 1.0f / 16129.0f;          // (8/127)*(0.125/127)
    float cb[4];
#pragma unroll
    for (int n = 0; n < 4; ++n) cb[n] = bias[gj0 + n * 16];
#pragma unroll
    for (int m = 0; m < 4; ++m)
#pragma unroll
      for (int r = 0; r < 4; ++r) {
        const int gi = gi0 + m * 16 + r;
#pragma unroll
        for (int n = 0; n < 4; ++n)
          Cf[(size_t)gi * NDIM + gj0 + n * 16] = (float)acc[m][n][r] * CO + cb[n];
      }
  }
}

// ---------------------------------------------------------------------------
// softmax: f32 A -> d_out, i8 A (q = round(exp*127)) + row scale -> ws
__global__ __launch_bounds__(256) void softmax_rows(const float* __restrict__ S,
                                                    float* __restrict__ Af,
                                                    signed char* __restrict__ Aq,
                                                    float* __restrict__ sRowA) {
  __shared__ float buf[Ltok];
  __shared__ float red[4];
  const int tid = threadIdx.x, lane = tid & 63, w = tid >> 6;
  const float LOG2E = 1.44269504088896f;
  const float* sr = S + (size_t)blockIdx.x * Ltok;
  float lmax = -3.4e38f;
  for (int j = tid * 4; j < Ltok; j += 1024) {
    float4 v = *(const float4*)&sr[j];
    *(float4*)&buf[j] = v;
    lmax = fmaxf(fmaxf(lmax, fmaxf(v.x, v.y)), fmaxf(v.z, v.w));
  }
#pragma unroll
  for (int off = 32; off > 0; off >>= 1) lmax = fmaxf(lmax, __shfl_xor(lmax, off));
  if (lane == 0) red[w] = lmax;
  __syncthreads();
  const float m = fmaxf(fmaxf(red[0], red[1]), fmaxf(red[2], red[3])) * LOG2E;
  __syncthreads();
  float lsum = 0.f;
  for (int j = tid * 4; j < Ltok; j += 1024) {
    lsum += exp2f(buf[j] * LOG2E - m) + exp2f(buf[j + 1] * LOG2E - m) +
            exp2f(buf[j + 2] * LOG2E - m) + exp2f(buf[j + 3] * LOG2E - m);
  }
#pragma unroll
  for (int off = 32; off > 0; off >>= 1) lsum += __shfl_xor(lsum, off);
  if (lane == 0) red[w] = lsum;
  __syncthreads();
  const float inv = 1.0f / (red[0] + red[1] + red[2] + red[3]);
  if (tid == 0) sRowA[blockIdx.x] = inv * (1.0f / 127.0f);
  float* arf = Af + (size_t)blockIdx.x * Ltok;
  signed char* arq = Aq + (size_t)blockIdx.x * Ltok;
  for (int j = tid * 4; j < Ltok; j += 1024) {
    float e0 = exp2f(buf[j] * LOG2E - m);
    float e1 = exp2f(buf[j + 1] * LOG2E - m);
    float e2 = exp2f(buf[j + 2] * LOG2E - m);
    float e3 = exp2f(buf[j + 3] * LOG2E - m);
    float4 aa; aa.x = e0 * inv; aa.y = e1 * inv; aa.z = e2 * inv; aa.w = e3 * inv;
    *(float4*)&arf[j] = aa;
    char4 q;
    q.x = (signed char)(int)rintf(e0 * 127.0f);
    q.y = (signed char)(int)rintf(e1 * 127.0f);
    q.z = (signed char)(int)rintf(e2 * 127.0f);
    q.w = (signed char)(int)rintf(e3 * 127.0f);
    *(char4*)&arq[j] = q;
  }
}

// ---------------------------------------------------------------------------
extern "C" void kernel_launch(void* const* d_in, const int* in_sizes, int n_in,
                              void* d_out, int out_size, void* d_ws, size_t ws_size,
                              hipStream_t stream) {
  const float* tok = (const float*)d_in[0];
  const float* ecc = (const float*)d_in[1];
  const float* Gm  = (const float*)d_in[2];
  const float* Rm  = (const float*)d_in[3];
  const float* Wv  = (const float*)d_in[4];
  const float* bv  = (const float*)d_in[5];
  const float* Wo  = (const float*)d_in[6];
  const float* bo  = (const float*)d_in[7];
  const int*   pos = (const int*)d_in[8];
  const int*   dep = (const int*)d_in[9];

  float* out_f = (float*)d_out;                    // [L][D] f32
  float* A_f   = out_f + (size_t)Ltok * Dm;        // [L][L] f32
  float* S_f   = A_f + (size_t)Ltok * Ltok;        // [L][L] f32

  char* ws = (char*)d_ws;
  size_t off = 0;
  auto alloc = [&](size_t bytes) {
    void* p = ws + off; off = (off + bytes + 255) & ~(size_t)255; return p;
  };
  signed char* Tq  = (signed char*)alloc((size_t)Ltok * Dm);     //  8 MB
  signed char* Wvq = (signed char*)alloc((size_t)Dm * Dm);       //  4 MB
  signed char* Woq = (signed char*)alloc((size_t)Dm * Dm);       //  4 MB
  signed char* Vtq = (signed char*)alloc((size_t)Dm * Ltok);     //  8 MB
  signed char* Aq  = (signed char*)alloc((size_t)Ltok * Ltok);   // 16 MB
  signed char* AVq = (signed char*)alloc((size_t)Ltok * Dm);     //  8 MB
  float4* tokf4 = (float4*)alloc(Ltok * 16);
  float*  sGR  = (float*)alloc(64 * 4);
  float*  sRowA = (float*)alloc(Ltok * 4);

  prep_tokens<<<Ltok, 256, 0, stream>>>(tok, ecc, pos, dep, Tq, tokf4);
  cast_f32_i8<<<(Dm * Dm) / 1024, 256, 0, stream>>>(Wv, Wvq, Dm * Dm);
  cast_f32_i8<<<(Dm * Dm) / 1024, 256, 0, stream>>>(Wo, Woq, Dm * Dm);
  small_prep<<<1, 64, 0, stream>>>(Gm, Rm, sGR);

  // scores f32 = (Tq . Tq) * S2 * c_ij  (256x256 i8 tile, 16x16 = 256 blocks)
  gemm8i<<<dim3(Ltok / 256, Ltok / 256), 512, 0, stream>>>(
      Tq, S_f, tokf4, sGR);
  // A = softmax(scores): f32 -> d_out, i8 + row scale -> ws
  softmax_rows<<<Ltok, 256, 0, stream>>>(S_f, A_f, Aq, sRowA);

  // V^T[d][l] i8 = quant(Wvq . Tq * CV + bv)   (grid 16x16 = 256 blocks)
  gemm4i<1, Ltok, Dm><<<dim3(Ltok / 256, Dm / 128), 512, 0, stream>>>(
      Wvq, Tq, Vtq, nullptr, nullptr, bv);

  // AV i8 = quant(Aq @ Vtq * sRow)   (grid 8x32 = 256 blocks)
  gemm4i<0, Dm, Ltok><<<dim3(Dm / 256, Ltok / 128), 512, 0, stream>>>(
      Aq, Vtq, AVq, nullptr, sRowA, nullptr);

  // out f32 = AVq @ Woq * CO + bo   (grid 8x32 = 256 blocks)
  gemm4i<2, Dm, Dm><<<dim3(Dm / 256, Ltok / 128), 512, 0, stream>>>(
      AVq, Woq, nullptr, out_f, nullptr, bo);
}